// Round 2
// baseline (924.226 us; speedup 1.0000x reference)
//
#include <hip/hip_runtime.h>

using bf16x8 = __attribute__((ext_vector_type(8))) __bf16;
using u16x8  = __attribute__((ext_vector_type(8))) unsigned short;
using f32x4  = __attribute__((ext_vector_type(4))) float;

__device__ __forceinline__ unsigned short f2bf(float f){
  unsigned int u = __float_as_uint(f);
  u += 0x7fffu + ((u >> 16) & 1u);     // round-to-nearest-even
  return (unsigned short)(u >> 16);
}
__device__ __forceinline__ float bf2f(unsigned short h){
  return __uint_as_float(((unsigned int)h) << 16);
}

// ---------------- weight fp32 -> bf16 convert ----------------
__global__ __launch_bounds__(256) void cvt_bf16(const float* __restrict__ s,
                                                unsigned short* __restrict__ d, int n){
  int i = blockIdx.x * 256 + threadIdx.x;
  if (i < n) d[i] = f2bf(s[i]);
}

// ---------------- front (amp): h = gelu(LN(x@aW1.T + b1)) ----------------
// R7: per-thread contiguous j = tid*16+k -> f32x4 weight loads, u16x8 stores.
__global__ __launch_bounds__(256) void front_amp_kernel(
    const float* __restrict__ x,
    const float* __restrict__ W1, const float* __restrict__ b1,
    const float* __restrict__ g1, const float* __restrict__ be1,
    unsigned short* __restrict__ h)
{
  __shared__ float red[256];
  __shared__ float red2[256];
  __shared__ float s_mean, s_inv;
  const int row = blockIdx.x;
  const int tid = threadIdx.x;
  const float x0 = x[row * 2 + 0];
  const float x1 = x[row * 2 + 1];

  const f32x4* W4 = (const f32x4*)(W1 + (size_t)tid * 32);   // 8 x f32x4
  float va[16];
  float sum = 0.f, sq = 0.f;
#pragma unroll
  for (int i4 = 0; i4 < 4; i4++){
    f32x4 b4 = *(const f32x4*)(b1 + tid * 16 + i4 * 4);
    f32x4 wa = W4[i4 * 2], wb = W4[i4 * 2 + 1];
    float v0 = x0 * wa[0] + x1 * wa[1] + b4[0];
    float v1 = x0 * wa[2] + x1 * wa[3] + b4[1];
    float v2 = x0 * wb[0] + x1 * wb[1] + b4[2];
    float v3 = x0 * wb[2] + x1 * wb[3] + b4[3];
    va[i4*4+0] = v0; va[i4*4+1] = v1; va[i4*4+2] = v2; va[i4*4+3] = v3;
    sum += v0 + v1 + v2 + v3;
    sq  += v0*v0 + v1*v1 + v2*v2 + v3*v3;
  }
  red[tid] = sum; red2[tid] = sq; __syncthreads();
  for (int s = 128; s > 0; s >>= 1){
    if (tid < s){ red[tid] += red[tid + s]; red2[tid] += red2[tid + s]; }
    __syncthreads();
  }
  if (tid == 0){
    float m = red[0] * (1.0f / 4096.0f);
    float v = red2[0] * (1.0f / 4096.0f) - m * m;
    s_mean = m; s_inv = rsqrtf(v + 1e-5f);
  }
  __syncthreads();
  float mean = s_mean, inv = s_inv;
#pragma unroll
  for (int i8 = 0; i8 < 2; i8++){
    f32x4 ga = *(const f32x4*)(g1  + tid * 16 + i8 * 8);
    f32x4 gb = *(const f32x4*)(g1  + tid * 16 + i8 * 8 + 4);
    f32x4 ba = *(const f32x4*)(be1 + tid * 16 + i8 * 8);
    f32x4 bb = *(const f32x4*)(be1 + tid * 16 + i8 * 8 + 4);
    u16x8 o;
#pragma unroll
    for (int k = 0; k < 8; k++){
      float gk = (k < 4) ? ga[k] : gb[k - 4];
      float bk = (k < 4) ? ba[k] : bb[k - 4];
      float y = (va[i8 * 8 + k] - mean) * inv * gk + bk;
      float ge = 0.5f * y * (1.0f + erff(y * 0.70710678118654752f));
      o[k] = f2bf(ge);
    }
    *(u16x8*)&h[(size_t)row * 4096 + tid * 16 + i8 * 8] = o;
  }
}

// ---------------- front (phase): p = silu(LN(x@pW1.T + b1)) ----------------
__global__ __launch_bounds__(256) void front_ph_kernel(
    const float* __restrict__ x,
    const float* __restrict__ W1, const float* __restrict__ b1,
    const float* __restrict__ g1, const float* __restrict__ be1,
    unsigned short* __restrict__ p)
{
  __shared__ float red[256];
  __shared__ float red2[256];
  __shared__ float s_mean, s_inv;
  const int row = blockIdx.x;
  const int tid = threadIdx.x;
  const float x0 = x[row * 2 + 0];
  const float x1 = x[row * 2 + 1];

  const f32x4* W4 = (const f32x4*)(W1 + (size_t)tid * 16);   // 4 x f32x4
  float vp[8];
  float sum = 0.f, sq = 0.f;
#pragma unroll
  for (int i4 = 0; i4 < 2; i4++){
    f32x4 b4 = *(const f32x4*)(b1 + tid * 8 + i4 * 4);
    f32x4 wa = W4[i4 * 2], wb = W4[i4 * 2 + 1];
    float v0 = x0 * wa[0] + x1 * wa[1] + b4[0];
    float v1 = x0 * wa[2] + x1 * wa[3] + b4[1];
    float v2 = x0 * wb[0] + x1 * wb[1] + b4[2];
    float v3 = x0 * wb[2] + x1 * wb[3] + b4[3];
    vp[i4*4+0] = v0; vp[i4*4+1] = v1; vp[i4*4+2] = v2; vp[i4*4+3] = v3;
    sum += v0 + v1 + v2 + v3;
    sq  += v0*v0 + v1*v1 + v2*v2 + v3*v3;
  }
  red[tid] = sum; red2[tid] = sq; __syncthreads();
  for (int s = 128; s > 0; s >>= 1){
    if (tid < s){ red[tid] += red[tid + s]; red2[tid] += red2[tid + s]; }
    __syncthreads();
  }
  if (tid == 0){
    float m = red[0] * (1.0f / 2048.0f);
    float v = red2[0] * (1.0f / 2048.0f) - m * m;
    s_mean = m; s_inv = rsqrtf(v + 1e-5f);
  }
  __syncthreads();
  float mean = s_mean, inv = s_inv;
  {
    f32x4 ga = *(const f32x4*)(g1  + tid * 8);
    f32x4 gb = *(const f32x4*)(g1  + tid * 8 + 4);
    f32x4 ba = *(const f32x4*)(be1 + tid * 8);
    f32x4 bb = *(const f32x4*)(be1 + tid * 8 + 4);
    u16x8 o;
#pragma unroll
    for (int k = 0; k < 8; k++){
      float gk = (k < 4) ? ga[k] : gb[k - 4];
      float bk = (k < 4) ? ba[k] : bb[k - 4];
      float y = (vp[k] - mean) * inv * gk + bk;
      float si = y / (1.0f + expf(-y));
      o[k] = f2bf(si);
    }
    *(u16x8*)&p[(size_t)row * 2048 + tid * 8] = o;
  }
}

// ---------------- row-wise LN + tanh, in place on bf16 (N=2048) ----------------
__global__ __launch_bounds__(256) void ln_tanh_kernel(
    unsigned short* __restrict__ c, const float* __restrict__ g,
    const float* __restrict__ be)
{
  __shared__ float red[256];
  __shared__ float red2[256];
  __shared__ float s_mean, s_inv;
  const size_t base = (size_t)blockIdx.x * 2048;
  const int tid = threadIdx.x;
  u16x8 cv = *(const u16x8*)&c[base + tid * 8];
  float v[8];
  float sum = 0.f, sq = 0.f;
#pragma unroll
  for (int k = 0; k < 8; k++){
    float t = bf2f(cv[k]);
    v[k] = t; sum += t; sq += t * t;
  }
  red[tid] = sum; red2[tid] = sq; __syncthreads();
  for (int s = 128; s > 0; s >>= 1){
    if (tid < s){ red[tid] += red[tid + s]; red2[tid] += red2[tid + s]; }
    __syncthreads();
  }
  if (tid == 0){
    float m = red[0] * (1.0f / 2048.0f);
    float vv = red2[0] * (1.0f / 2048.0f) - m * m;
    s_mean = m; s_inv = rsqrtf(vv + 1e-5f);
  }
  __syncthreads();
  float mean = s_mean, inv = s_inv;
  {
    f32x4 ga = *(const f32x4*)(g  + tid * 8);
    f32x4 gb = *(const f32x4*)(g  + tid * 8 + 4);
    f32x4 ba = *(const f32x4*)(be + tid * 8);
    f32x4 bb = *(const f32x4*)(be + tid * 8 + 4);
    u16x8 o;
#pragma unroll
    for (int k = 0; k < 8; k++){
      float gk = (k < 4) ? ga[k] : gb[k - 4];
      float bk = (k < 4) ? ba[k] : bb[k - 4];
      float y = (v[k] - mean) * inv * gk + bk;
      o[k] = f2bf(tanhf(y));
    }
    *(u16x8*)&c[base + tid * 8] = o;
  }
}

// ---------------- bf16 MFMA GEMM: C = A @ B^T (+epilogue) ----------------
// 256x256 block tile, BK=32, 512 thr = 8 waves (4m x 2n), wave = 64x128 out.
//
// R7 model: GEMM1 step time 2381cy = MFMA 1242 + LDS-read ~770-1150 + slop
// -> sitting at the ADDITIVE point (MfmaUtil 49 = 1242/2381). m201 evidence:
// phase-locked small quanta (barrier-paired read/MFMA phases + setprio) reach
// MFMA/(MFMA+LDS@128B/cy) = 62%. So: split each K-step into two phases
// {8 ds_read -> 16 MFMA} s_barrier {4 ds_read -> 16 MFMA}. Buffer/vmcnt
// ledger identical to R6's proven 4-buf 3-deep counted-vmcnt skeleton.
// EPI: 0 = bf16(val + bias[col])
//      1 = bf16((sin((val+bias)*rf0+rp0) + ry + tanh(rp2))/3)  [aux2=ry]
//      2 = bf16(cos(tanh(val+bias)*rf1 + rp1))                 [phase ry]
//      3 = f32(val + bias[col])                                [final]

#define WAITV8() asm volatile("s_waitcnt vmcnt(8)" ::: "memory")
#define WAITV4() asm volatile("s_waitcnt vmcnt(4)" ::: "memory")
#define WAITV0() asm volatile("s_waitcnt vmcnt(0)" ::: "memory")

template<int EPI>
__global__ __launch_bounds__(512, 2) void gemm_bt(
    const unsigned short* __restrict__ A, const unsigned short* __restrict__ B,
    void* __restrict__ outp, int M, int N, int K, int nT,
    const float* __restrict__ bias,
    const float* __restrict__ aux0, const float* __restrict__ aux1,
    const unsigned short* __restrict__ aux2)
{
  __shared__ __align__(16) char smem_raw[131072];  // 4 x 32KB staging; epilogue reuses [0,67.6K)
  unsigned short* S = (unsigned short*)smem_raw;

  const int tid  = threadIdx.x;
  const int wave = tid >> 6, lane = tid & 63;
  const int wm = wave >> 1, wn = wave & 1;     // wm 0..3 (64-row band), wn 0..1 (128-col band)
  const int lm = lane & 15, lq = lane >> 4;

  int lid = blockIdx.x;
  {
    const int nwg = gridDim.x;                 // 512 or 256 here: always %8==0
    if ((nwg & 7) == 0) lid = (lid & 7) * (nwg >> 3) + (lid >> 3);
  }
  const int m0 = (lid / nT) * 256, n0 = (lid % nT) * 256;

  f32x4 acc[4][8];
#pragma unroll
  for (int i = 0; i < 4; i++)
#pragma unroll
    for (int j = 0; j < 8; j++) acc[i][j] = (f32x4){0.f, 0.f, 0.f, 0.f};

  // staging: lane i covers row (wave*32 + i/4); the 16B unit it fetches from
  // global is XOR-swizzled by the row so that LDS unit u of row r holds
  // global unit u ^ ((r>>1)&3). glds LDS dest stays linear (HW requirement).
  const int lr = lane >> 2;
  const int lc = (((lane & 3) ^ ((lr >> 1) & 3)) << 3);
  const unsigned short* gA = A + (size_t)(m0 + wave * 32 + lr) * K + lc;
  const unsigned short* gB = B + (size_t)(n0 + wave * 32 + lr) * K + lc;
  const size_t rowK16 = (size_t)16 * K;

  auto stage = [&](int buf){
    unsigned short* lA = S + buf * 16384 + wave * 1024;
    unsigned short* lB = lA + 8192;
    __builtin_amdgcn_global_load_lds(
        (const __attribute__((address_space(1))) void*)gA,
        (__attribute__((address_space(3))) void*)lA, 16, 0, 0);
    __builtin_amdgcn_global_load_lds(
        (const __attribute__((address_space(1))) void*)(gA + rowK16),
        (__attribute__((address_space(3))) void*)(lA + 512), 16, 0, 0);
    __builtin_amdgcn_global_load_lds(
        (const __attribute__((address_space(1))) void*)gB,
        (__attribute__((address_space(3))) void*)lB, 16, 0, 0);
    __builtin_amdgcn_global_load_lds(
        (const __attribute__((address_space(1))) void*)(gB + rowK16),
        (__attribute__((address_space(3))) void*)(lB + 512), 16, 0, 0);
    gA += 32; gB += 32;
  };

  // ---- K loop: 4 bufs, 3 K-steps in flight, counted vmcnt, raw barriers,
  //      2 phase-locked halves per K-step ----
  const int nTk = K >> 5;
  stage(0); stage(1); stage(2);
  for (int t = 0; t < nTk; ++t){
    if (t + 2 < nTk)      WAITV8();
    else if (t + 1 < nTk) WAITV4();
    else                  WAITV0();
    __builtin_amdgcn_s_barrier();
    if (t + 3 < nTk) stage((t + 3) & 3);

    const int buf = t & 3;
    const unsigned short* sA = S + buf * 16384;
    const unsigned short* sB = sA + 8192;
    bf16x8 af[4], bfr[4];
    // ---- phase A: A-frags + B cols 0..63, C quadrants j=0..3 ----
#pragma unroll
    for (int q = 0; q < 4; q++){
      const int r = wm * 64 + q * 16 + lm;
      af[q] = *(const bf16x8*)&sA[r * 32 + ((lq ^ ((r >> 1) & 3)) << 3)];
    }
#pragma unroll
    for (int q = 0; q < 4; q++){
      const int r = wn * 128 + q * 16 + lm;
      bfr[q] = *(const bf16x8*)&sB[r * 32 + ((lq ^ ((r >> 1) & 3)) << 3)];
    }
    __builtin_amdgcn_s_setprio(1);
#pragma unroll
    for (int i = 0; i < 4; i++)
#pragma unroll
      for (int j = 0; j < 4; j++)
        acc[i][j] = __builtin_amdgcn_mfma_f32_16x16x32_bf16(af[i], bfr[j], acc[i][j], 0, 0, 0);
    __builtin_amdgcn_s_setprio(0);
    __builtin_amdgcn_sched_barrier(0);
    __builtin_amdgcn_s_barrier();          // phase-lock: LDS pipe <-> matrix pipe
    __builtin_amdgcn_sched_barrier(0);
    // ---- phase B: B cols 64..127, C quadrants j=4..7 (af reused) ----
#pragma unroll
    for (int q = 0; q < 4; q++){
      const int r = wn * 128 + 64 + q * 16 + lm;
      bfr[q] = *(const bf16x8*)&sB[r * 32 + ((lq ^ ((r >> 1) & 3)) << 3)];
    }
    __builtin_amdgcn_s_setprio(1);
#pragma unroll
    for (int i = 0; i < 4; i++)
#pragma unroll
      for (int j = 0; j < 4; j++)
        acc[i][j + 4] = __builtin_amdgcn_mfma_f32_16x16x32_bf16(af[i], bfr[j], acc[i][j + 4], 0, 0, 0);
    __builtin_amdgcn_s_setprio(0);
  }

  // ---- epilogue: per-wave LDS transpose -> coalesced stores ----
  __syncthreads();                 // all waves done reading staging LDS
  float* ew = (float*)smem_raw + wave * 2112;   // 16 rows x stride 132

#pragma unroll
  for (int i = 0; i < 4; i++){
    // phase 1: epilogue math (col params known), write fp32 to private LDS chunk
#pragma unroll
    for (int j = 0; j < 8; j++){
      const int col = n0 + wn * 128 + j * 16 + lm;
      float bcol = bias[col];
      float f0 = 0.f, p0 = 0.f, rzv = 0.f;
      if constexpr (EPI == 1){
        f0 = aux0[3 * col]; p0 = aux1[3 * col]; rzv = tanhf(aux1[3 * col + 2]);
      }
      if constexpr (EPI == 2){
        f0 = aux0[3 * col + 1]; p0 = aux1[3 * col + 1];
      }
#pragma unroll
      for (int r = 0; r < 4; r++){
        const float val = acc[i][j][r];
        float pre;
        if constexpr (EPI == 0 || EPI == 3)      pre = val + bcol;
        else if constexpr (EPI == 1)             pre = sinf((val + bcol) * f0 + p0) + rzv;
        else                                     pre = cosf(tanhf(val + bcol) * f0 + p0);
        ew[(lq * 4 + r) * 132 + j * 16 + lm] = pre;
      }
    }
    // phase 2: read back rows, store coalesced (same wave wrote -> no barrier)
    if constexpr (EPI != 3){
#pragma unroll
      for (int s = 0; s < 4; s++){
        const int lrow = 4 * s + lq;
        const int grow = m0 + wm * 64 + i * 16 + lrow;
        const float* src = ew + lrow * 132 + lm * 8;
        f32x4 v0 = *(const f32x4*)(src);
        f32x4 v1 = *(const f32x4*)(src + 4);
        const size_t gidx = (size_t)grow * N + n0 + wn * 128 + lm * 8;
        u16x8 o;
        if constexpr (EPI == 1){
          u16x8 ry8 = *(const u16x8*)&aux2[gidx];
#pragma unroll
          for (int t = 0; t < 4; t++){
            o[t]     = f2bf((v0[t] + bf2f(ry8[t]))     * (1.0f / 3.0f));
            o[t + 4] = f2bf((v1[t] + bf2f(ry8[t + 4])) * (1.0f / 3.0f));
          }
        } else {
#pragma unroll
          for (int t = 0; t < 4; t++){
            o[t] = f2bf(v0[t]); o[t + 4] = f2bf(v1[t]);
          }
        }
        *(u16x8*)&((unsigned short*)outp)[gidx] = o;
      }
    } else {
#pragma unroll
      for (int s = 0; s < 8; s++){
        const int lrow = 2 * s + (lane >> 5);
        const int grow = m0 + wm * 64 + i * 16 + lrow;
        const int lcol = (lane & 31) * 4;
        f32x4 v = *(const f32x4*)(ew + lrow * 132 + lcol);
        *(f32x4*)&((float*)outp)[(size_t)grow * N + n0 + wn * 128 + lcol] = v;
      }
    }
  }
}

extern "C" void kernel_launch(void* const* d_in, const int* in_sizes, int n_in,
                              void* d_out, int out_size, void* d_ws, size_t ws_size,
                              hipStream_t stream)
{
  const float* x    = (const float*)d_in[0];
  const float* aW1  = (const float*)d_in[1];
  const float* ab1  = (const float*)d_in[2];
  const float* ag1  = (const float*)d_in[3];
  const float* abe1 = (const float*)d_in[4];
  const float* aW2  = (const float*)d_in[5];
  const float* ab2  = (const float*)d_in[6];
  const float* ag2  = (const float*)d_in[7];
  const float* abe2 = (const float*)d_in[8];
  const float* aW3  = (const float*)d_in[9];
  const float* ab3  = (const float*)d_in[10];
  const float* pW1  = (const float*)d_in[11];
  const float* pb1  = (const float*)d_in[12];
  const float* pg1  = (const float*)d_in[13];
  const float* pbe1 = (const float*)d_in[14];
  const float* pW2  = (const float*)d_in[15];
  const float* pb2  = (const float*)d_in[16];
  const float* rfreq  = (const float*)d_in[17];
  const float* rphase = (const float*)d_in[18];
  const float* aiw  = (const float*)d_in[19];
  const float* aib  = (const float*)d_in[20];
  const float* aow  = (const float*)d_in[21];
  const float* aob  = (const float*)d_in[22];

  const int B = 16384, Q = 1024;

  // ---- workspace layout (~188 MB; c2 lives in d_out) ----
  char* ws = (char*)d_ws;
  size_t off = 0;
  auto alloc = [&](size_t bytes) -> char* {
    char* ptr = ws + off; off += (bytes + 255) & ~(size_t)255; return ptr;
  };
  unsigned short* Wb2  = (unsigned short*)alloc((size_t)2 * Q * 4 * Q * 2); // 16 MB
  unsigned short* Wb3  = (unsigned short*)alloc((size_t)Q * 2 * Q * 2);     //  4 MB
  unsigned short* PWb2 = (unsigned short*)alloc((size_t)Q * 2 * Q * 2);     //  4 MB
  unsigned short* WVb  = (unsigned short*)alloc((size_t)Q * Q * 2);         //  2 MB
  unsigned short* WOb  = (unsigned short*)alloc((size_t)Q * Q * 2);         //  2 MB
  unsigned short* R1   = (unsigned short*)alloc((size_t)B * 4 * Q * 2);     // 128 MB shared region
  unsigned short* ry   = (unsigned short*)alloc((size_t)B * Q * 2);         //  32 MB

  // R1 overlays (time-disjoint):
  unsigned short* p  = R1;                      // phase act (dead after gemm_ph)
  unsigned short* h  = R1;                      // amp act   (dead after gemm1)
  unsigned short* qs = R1;                      // combine out (after h dead)
  unsigned short* v  = R1 + (size_t)B * Q;      // v (after h dead)
  unsigned short* c2 = (unsigned short*)d_out;  // borrow output buffer (64 MB), dead before final GEMM

  // weight converts (bf16)
  cvt_bf16<<<(2*Q*4*Q + 255) / 256, 256, 0, stream>>>(aW2, Wb2, 2*Q*4*Q);
  cvt_bf16<<<(Q*2*Q + 255) / 256, 256, 0, stream>>>(aW3, Wb3, Q*2*Q);
  cvt_bf16<<<(Q*2*Q + 255) / 256, 256, 0, stream>>>(pW2, PWb2, Q*2*Q);
  cvt_bf16<<<(Q*Q + 255) / 256, 256, 0, stream>>>(aiw + (size_t)2*Q*Q, WVb, Q*Q);
  cvt_bf16<<<(Q*Q + 255) / 256, 256, 0, stream>>>(aow, WOb, Q*Q);

  const float* rf4 = rfreq  + (size_t)4 * Q * 3;   // rot_freq[-1]
  const float* rp4 = rphase + (size_t)4 * Q * 3;   // rot_phase[-1]

  const int mT = B / 256;          // 64
  const int nT1 = 2 * Q / 256;     // 8
  const int nTq = Q / 256;         // 4

  // ---- phase path first (so p's region can be reused by h) ----
  front_ph_kernel<<<B, 256, 0, stream>>>(x, pW1, pb1, pg1, pbe1, p);
  // ry = cos(tanh(p@pW2.T + pb2)*rf1 + rp1)   (N=1024, K=2048)
  gemm_bt<2><<<nTq * mT, 512, 0, stream>>>(p, PWb2, ry, B, Q, 2*Q, nTq,
                                           pb2, rf4, rp4, nullptr);

  // ---- amp path ----
  front_amp_kernel<<<B, 256, 0, stream>>>(x, aW1, ab1, ag1, abe1, h);
  // GEMM1: c2 = h @ aW2.T + b2   (M=16384, N=2048, K=4096), bf16 out (in d_out)
  gemm_bt<0><<<nT1 * mT, 512, 0, stream>>>(h, Wb2, c2, B, 2*Q, 4*Q, nT1,
                                           ab2, nullptr, nullptr, nullptr);
  // h2 = tanh(LN(c2)) in place
  ln_tanh_kernel<<<B, 256, 0, stream>>>(c2, ag2, abe2);

  // GEMM2 (fused combine): qs = (sin((c2h@aW3.T+b3)*rf0+rp0) + ry + tanh(rp2))/3
  gemm_bt<1><<<nTq * mT, 512, 0, stream>>>(c2, Wb3, qs, B, Q, 2*Q, nTq,
                                           ab3, rf4, rp4, ry);
  // GEMM4: v = qs @ aiw[2Q:].T + aib[2Q:]   (N=1024, K=1024)
  gemm_bt<0><<<nTq * mT, 512, 0, stream>>>(qs, WVb, v, B, Q, Q, nTq,
                                           aib + 2*Q, nullptr, nullptr, nullptr);
  // GEMM5: out = v @ aow.T + aob   (N=1024, K=1024), fp32 out (overwrites dead c2)
  gemm_bt<3><<<nTq * mT, 512, 0, stream>>>(v, WOb, d_out, B, Q, Q, nTq,
                                           aob, nullptr, nullptr, nullptr);
}

// Round 7
// 907.302 us; speedup vs baseline: 1.0187x; 1.0187x over previous
//
#include <hip/hip_runtime.h>

using bf16x8 = __attribute__((ext_vector_type(8))) __bf16;
using u16x8  = __attribute__((ext_vector_type(8))) unsigned short;
using f32x4  = __attribute__((ext_vector_type(4))) float;

__device__ __forceinline__ unsigned short f2bf(float f){
  unsigned int u = __float_as_uint(f);
  u += 0x7fffu + ((u >> 16) & 1u);     // round-to-nearest-even
  return (unsigned short)(u >> 16);
}
__device__ __forceinline__ float bf2f(unsigned short h){
  return __uint_as_float(((unsigned int)h) << 16);
}

// ---------------- weight fp32 -> bf16 convert ----------------
__global__ __launch_bounds__(256) void cvt_bf16(const float* __restrict__ s,
                                                unsigned short* __restrict__ d, int n){
  int i = blockIdx.x * 256 + threadIdx.x;
  if (i < n) d[i] = f2bf(s[i]);
}

// ---------------- front (amp): h = gelu(LN(x@aW1.T + b1)) ----------------
__global__ __launch_bounds__(256) void front_amp_kernel(
    const float* __restrict__ x,
    const float* __restrict__ W1, const float* __restrict__ b1,
    const float* __restrict__ g1, const float* __restrict__ be1,
    unsigned short* __restrict__ h)
{
  __shared__ float red[256];
  __shared__ float red2[256];
  __shared__ float s_mean, s_inv;
  const int row = blockIdx.x;
  const int tid = threadIdx.x;
  const float x0 = x[row * 2 + 0];
  const float x1 = x[row * 2 + 1];

  const f32x4* W4 = (const f32x4*)(W1 + (size_t)tid * 32);   // 8 x f32x4
  float va[16];
  float sum = 0.f, sq = 0.f;
#pragma unroll
  for (int i4 = 0; i4 < 4; i4++){
    f32x4 b4 = *(const f32x4*)(b1 + tid * 16 + i4 * 4);
    f32x4 wa = W4[i4 * 2], wb = W4[i4 * 2 + 1];
    float v0 = x0 * wa[0] + x1 * wa[1] + b4[0];
    float v1 = x0 * wa[2] + x1 * wa[3] + b4[1];
    float v2 = x0 * wb[0] + x1 * wb[1] + b4[2];
    float v3 = x0 * wb[2] + x1 * wb[3] + b4[3];
    va[i4*4+0] = v0; va[i4*4+1] = v1; va[i4*4+2] = v2; va[i4*4+3] = v3;
    sum += v0 + v1 + v2 + v3;
    sq  += v0*v0 + v1*v1 + v2*v2 + v3*v3;
  }
  red[tid] = sum; red2[tid] = sq; __syncthreads();
  for (int s = 128; s > 0; s >>= 1){
    if (tid < s){ red[tid] += red[tid + s]; red2[tid] += red2[tid + s]; }
    __syncthreads();
  }
  if (tid == 0){
    float m = red[0] * (1.0f / 4096.0f);
    float v = red2[0] * (1.0f / 4096.0f) - m * m;
    s_mean = m; s_inv = rsqrtf(v + 1e-5f);
  }
  __syncthreads();
  float mean = s_mean, inv = s_inv;
#pragma unroll
  for (int i8 = 0; i8 < 2; i8++){
    f32x4 ga = *(const f32x4*)(g1  + tid * 16 + i8 * 8);
    f32x4 gb = *(const f32x4*)(g1  + tid * 16 + i8 * 8 + 4);
    f32x4 ba = *(const f32x4*)(be1 + tid * 16 + i8 * 8);
    f32x4 bb = *(const f32x4*)(be1 + tid * 16 + i8 * 8 + 4);
    u16x8 o;
#pragma unroll
    for (int k = 0; k < 8; k++){
      float gk = (k < 4) ? ga[k] : gb[k - 4];
      float bk = (k < 4) ? ba[k] : bb[k - 4];
      float y = (va[i8 * 8 + k] - mean) * inv * gk + bk;
      float ge = 0.5f * y * (1.0f + erff(y * 0.70710678118654752f));
      o[k] = f2bf(ge);
    }
    *(u16x8*)&h[(size_t)row * 4096 + tid * 16 + i8 * 8] = o;
  }
}

// ---------------- front (phase): p = silu(LN(x@pW1.T + b1)) ----------------
__global__ __launch_bounds__(256) void front_ph_kernel(
    const float* __restrict__ x,
    const float* __restrict__ W1, const float* __restrict__ b1,
    const float* __restrict__ g1, const float* __restrict__ be1,
    unsigned short* __restrict__ p)
{
  __shared__ float red[256];
  __shared__ float red2[256];
  __shared__ float s_mean, s_inv;
  const int row = blockIdx.x;
  const int tid = threadIdx.x;
  const float x0 = x[row * 2 + 0];
  const float x1 = x[row * 2 + 1];

  const f32x4* W4 = (const f32x4*)(W1 + (size_t)tid * 16);   // 4 x f32x4
  float vp[8];
  float sum = 0.f, sq = 0.f;
#pragma unroll
  for (int i4 = 0; i4 < 2; i4++){
    f32x4 b4 = *(const f32x4*)(b1 + tid * 8 + i4 * 4);
    f32x4 wa = W4[i4 * 2], wb = W4[i4 * 2 + 1];
    float v0 = x0 * wa[0] + x1 * wa[1] + b4[0];
    float v1 = x0 * wa[2] + x1 * wa[3] + b4[1];
    float v2 = x0 * wb[0] + x1 * wb[1] + b4[2];
    float v3 = x0 * wb[2] + x1 * wb[3] + b4[3];
    vp[i4*4+0] = v0; vp[i4*4+1] = v1; vp[i4*4+2] = v2; vp[i4*4+3] = v3;
    sum += v0 + v1 + v2 + v3;
    sq  += v0*v0 + v1*v1 + v2*v2 + v3*v3;
  }
  red[tid] = sum; red2[tid] = sq; __syncthreads();
  for (int s = 128; s > 0; s >>= 1){
    if (tid < s){ red[tid] += red[tid + s]; red2[tid] += red2[tid + s]; }
    __syncthreads();
  }
  if (tid == 0){
    float m = red[0] * (1.0f / 2048.0f);
    float v = red2[0] * (1.0f / 2048.0f) - m * m;
    s_mean = m; s_inv = rsqrtf(v + 1e-5f);
  }
  __syncthreads();
  float mean = s_mean, inv = s_inv;
  {
    f32x4 ga = *(const f32x4*)(g1  + tid * 8);
    f32x4 gb = *(const f32x4*)(g1  + tid * 8 + 4);
    f32x4 ba = *(const f32x4*)(be1 + tid * 8);
    f32x4 bb = *(const f32x4*)(be1 + tid * 8 + 4);
    u16x8 o;
#pragma unroll
    for (int k = 0; k < 8; k++){
      float gk = (k < 4) ? ga[k] : gb[k - 4];
      float bk = (k < 4) ? ba[k] : bb[k - 4];
      float y = (vp[k] - mean) * inv * gk + bk;
      float si = y / (1.0f + expf(-y));
      o[k] = f2bf(si);
    }
    *(u16x8*)&p[(size_t)row * 2048 + tid * 8] = o;
  }
}

// ---------------- row-wise LN + tanh, in place on bf16 (N=2048) ----------------
__global__ __launch_bounds__(256) void ln_tanh_kernel(
    unsigned short* __restrict__ c, const float* __restrict__ g,
    const float* __restrict__ be)
{
  __shared__ float red[256];
  __shared__ float red2[256];
  __shared__ float s_mean, s_inv;
  const size_t base = (size_t)blockIdx.x * 2048;
  const int tid = threadIdx.x;
  u16x8 cv = *(const u16x8*)&c[base + tid * 8];
  float v[8];
  float sum = 0.f, sq = 0.f;
#pragma unroll
  for (int k = 0; k < 8; k++){
    float t = bf2f(cv[k]);
    v[k] = t; sum += t; sq += t * t;
  }
  red[tid] = sum; red2[tid] = sq; __syncthreads();
  for (int s = 128; s > 0; s >>= 1){
    if (tid < s){ red[tid] += red[tid + s]; red2[tid] += red2[tid + s]; }
    __syncthreads();
  }
  if (tid == 0){
    float m = red[0] * (1.0f / 2048.0f);
    float vv = red2[0] * (1.0f / 2048.0f) - m * m;
    s_mean = m; s_inv = rsqrtf(vv + 1e-5f);
  }
  __syncthreads();
  float mean = s_mean, inv = s_inv;
  {
    f32x4 ga = *(const f32x4*)(g  + tid * 8);
    f32x4 gb = *(const f32x4*)(g  + tid * 8 + 4);
    f32x4 ba = *(const f32x4*)(be + tid * 8);
    f32x4 bb = *(const f32x4*)(be + tid * 8 + 4);
    u16x8 o;
#pragma unroll
    for (int k = 0; k < 8; k++){
      float gk = (k < 4) ? ga[k] : gb[k - 4];
      float bk = (k < 4) ? ba[k] : bb[k - 4];
      float y = (v[k] - mean) * inv * gk + bk;
      o[k] = f2bf(tanhf(y));
    }
    *(u16x8*)&c[base + tid * 8] = o;
  }
}

// ---------------- bf16 MFMA GEMM: C = A @ B^T (+epilogue) ----------------
// 256x256 block tile, BK=32, 512 thr = 8 waves (4m x 2n), wave = 64x128 out.
//
// R12 = R11 with the REAL bug fixed: R9-R11 called stage(t+3)/stage(t+4)
// WITHOUT the &3 mask -> LDS dest up to 4MB into a 128KB allocation. Staged
// tiles never landed (absmax 1.17 = R3's signature) and OOB glds dests
// plausibly faulted the GPU (the two "container failed twice" rounds).
// R3 had the mask but raced (wait-after-barrier); R9+ fixed the ordering but
// dropped the mask. This round has BOTH: masked bufs + wait-THEN-barrier.
// Ledger (re-traced with masks): at even-half-t barrier pending prefetch
// ds_reads target buf t&3, stage targets (t+3)&3 (differ); at odd-half
// barrier pending reads target (t+1)&3, stage targets t&3 (differ); every
// overwritten buffer's readers were lgkm-consumed by the mfma cluster before
// that barrier in all waves. B-frag double-buffer only (bfA/bfB, ~238 regs,
// no spill): 8 of 12 ds_reads/step overlap the prior step's MFMA cluster.
// EPI: 0 = bf16(val + bias[col])
//      1 = bf16((sin((val+bias)*rf0+rp0) + ry + tanh(rp2))/3)  [aux2=ry]
//      2 = bf16(cos(tanh(val+bias)*rf1 + rp1))                 [phase ry]
//      3 = f32(val + bias[col])                                [final]

#define WAITV4() asm volatile("s_waitcnt vmcnt(4)" ::: "memory")
#define WAITV8() asm volatile("s_waitcnt vmcnt(8)" ::: "memory")
#define WAITV0() asm volatile("s_waitcnt vmcnt(0)" ::: "memory")

template<int EPI>
__global__ __launch_bounds__(512, 2) void gemm_bt(
    const unsigned short* __restrict__ A, const unsigned short* __restrict__ B,
    void* __restrict__ outp, int M, int N, int K, int nT,
    const float* __restrict__ bias,
    const float* __restrict__ aux0, const float* __restrict__ aux1,
    const unsigned short* __restrict__ aux2)
{
  __shared__ __align__(16) char smem_raw[131072];  // 4 x 32KB staging; epilogue reuses [0,67.6K)
  unsigned short* S = (unsigned short*)smem_raw;

  const int tid  = threadIdx.x;
  const int wave = tid >> 6, lane = tid & 63;
  const int wm = wave >> 1, wn = wave & 1;     // wm 0..3 (64-row band), wn 0..1 (128-col band)
  const int lm = lane & 15, lq = lane >> 4;

  int lid = blockIdx.x;
  {
    const int nwg = gridDim.x;                 // 512 or 256 here: always %8==0
    if ((nwg & 7) == 0) lid = (lid & 7) * (nwg >> 3) + (lid >> 3);
  }
  const int m0 = (lid / nT) * 256, n0 = (lid % nT) * 256;

  f32x4 acc[4][8];
#pragma unroll
  for (int i = 0; i < 4; i++)
#pragma unroll
    for (int j = 0; j < 8; j++) acc[i][j] = (f32x4){0.f, 0.f, 0.f, 0.f};

  // staging: lane i covers row (wave*32 + i/4); the 16B unit it fetches from
  // global is XOR-swizzled by the row so that LDS unit u of row r holds
  // global unit u ^ ((r>>1)&3). glds LDS dest stays linear (HW requirement).
  const int lr = lane >> 2;
  const int lc = (((lane & 3) ^ ((lr >> 1) & 3)) << 3);
  const unsigned short* gA = A + (size_t)(m0 + wave * 32 + lr) * K + lc;
  const unsigned short* gB = B + (size_t)(n0 + wave * 32 + lr) * K + lc;
  const size_t rowK16 = (size_t)16 * K;

  auto stage = [&](int buf){
    unsigned short* lA = S + buf * 16384 + wave * 1024;
    unsigned short* lB = lA + 8192;
    __builtin_amdgcn_global_load_lds(
        (const __attribute__((address_space(1))) void*)gA,
        (__attribute__((address_space(3))) void*)lA, 16, 0, 0);
    __builtin_amdgcn_global_load_lds(
        (const __attribute__((address_space(1))) void*)(gA + rowK16),
        (__attribute__((address_space(3))) void*)(lA + 512), 16, 0, 0);
    __builtin_amdgcn_global_load_lds(
        (const __attribute__((address_space(1))) void*)gB,
        (__attribute__((address_space(3))) void*)lB, 16, 0, 0);
    __builtin_amdgcn_global_load_lds(
        (const __attribute__((address_space(1))) void*)(gB + rowK16),
        (__attribute__((address_space(3))) void*)(lB + 512), 16, 0, 0);
    gA += 32; gB += 32;
  };

  auto readA = [&](int buf, bf16x8* af){
    const unsigned short* sA = S + buf * 16384;
#pragma unroll
    for (int q = 0; q < 4; q++){
      const int r = wm * 64 + q * 16 + lm;
      af[q] = *(const bf16x8*)&sA[r * 32 + ((lq ^ ((r >> 1) & 3)) << 3)];
    }
  };
  auto readB = [&](int buf, bf16x8* bfr){
    const unsigned short* sB = S + buf * 16384 + 8192;
#pragma unroll
    for (int q = 0; q < 8; q++){
      const int r = wn * 128 + q * 16 + lm;
      bfr[q] = *(const bf16x8*)&sB[r * 32 + ((lq ^ ((r >> 1) & 3)) << 3)];
    }
  };

  auto mfmaAll = [&](const bf16x8* af, const bf16x8* bfr){
    __builtin_amdgcn_s_setprio(1);
#pragma unroll
    for (int i = 0; i < 4; i++)
#pragma unroll
      for (int j = 0; j < 8; j++)
        acc[i][j] = __builtin_amdgcn_mfma_f32_16x16x32_bf16(af[i], bfr[j], acc[i][j], 0, 0, 0);
    __builtin_amdgcn_s_setprio(0);
  };

  // ---- K loop: 4 bufs, counted vmcnt BEFORE barrier, 1 barrier/K-step,
  //      B-frag double-buffer across steps, A-frags read at use ----
  const int nTk = K >> 5;          // 128/64/32 here - always even
  bf16x8 af[4], bfA[8], bfB[8];
  stage(0); stage(1); stage(2);    // 12 outstanding
  WAITV8();                        // stage 0 complete (own wave)
  __builtin_amdgcn_s_barrier();    // all waves' stage 0 visible
  readB(0, bfA);
  for (int t = 0; t < nTk; t += 2){
    // ---- even half: compute buf t (bfA); prefetch bfB <- buf t+1 ----
    if (t + 2 < nTk) WAITV4(); else WAITV0();   // certify stage t+1 (own wave)
    __builtin_amdgcn_s_barrier();  // cross-wave: stage t+1 visible; buf (t-1)&3 reads done
    if (t + 3 < nTk) stage((t + 3) & 3);
    readB((t + 1) & 3, bfB);
    readA(t & 3, af);
    mfmaAll(af, bfA);
    // ---- odd half: compute buf t+1 (bfB); prefetch bfA <- buf t+2 ----
    if (t + 2 < nTk){
      if (t + 3 < nTk) WAITV4(); else WAITV0(); // certify stage t+2 (own wave)
    }
    __builtin_amdgcn_s_barrier();  // cross-wave: stage t+2 visible; buf t&3 reads done
    if (t + 4 < nTk) stage((t + 4) & 3);
    if (t + 2 < nTk) readB((t + 2) & 3, bfA);
    readA((t + 1) & 3, af);
    mfmaAll(af, bfB);
  }

  // ---- epilogue: per-wave LDS transpose -> coalesced stores ----
  __syncthreads();                 // all waves done reading staging LDS
  float* ew = (float*)smem_raw + wave * 2112;   // 16 rows x stride 132

#pragma unroll
  for (int i = 0; i < 4; i++){
    // phase 1: epilogue math (col params known), write fp32 to private LDS chunk
#pragma unroll
    for (int j = 0; j < 8; j++){
      const int col = n0 + wn * 128 + j * 16 + lm;
      float bcol = bias[col];
      float f0 = 0.f, p0 = 0.f, rzv = 0.f;
      if constexpr (EPI == 1){
        f0 = aux0[3 * col]; p0 = aux1[3 * col]; rzv = tanhf(aux1[3 * col + 2]);
      }
      if constexpr (EPI == 2){
        f0 = aux0[3 * col + 1]; p0 = aux1[3 * col + 1];
      }
#pragma unroll
      for (int r = 0; r < 4; r++){
        const float val = acc[i][j][r];
        float pre;
        if constexpr (EPI == 0 || EPI == 3)      pre = val + bcol;
        else if constexpr (EPI == 1)             pre = sinf((val + bcol) * f0 + p0) + rzv;
        else                                     pre = cosf(tanhf(val + bcol) * f0 + p0);
        ew[(lq * 4 + r) * 132 + j * 16 + lm] = pre;
      }
    }
    // phase 2: read back rows, store coalesced (same wave wrote -> no barrier)
    if constexpr (EPI != 3){
#pragma unroll
      for (int s = 0; s < 4; s++){
        const int lrow = 4 * s + lq;
        const int grow = m0 + wm * 64 + i * 16 + lrow;
        const float* src = ew + lrow * 132 + lm * 8;
        f32x4 v0 = *(const f32x4*)(src);
        f32x4 v1 = *(const f32x4*)(src + 4);
        const size_t gidx = (size_t)grow * N + n0 + wn * 128 + lm * 8;
        u16x8 o;
        if constexpr (EPI == 1){
          u16x8 ry8 = *(const u16x8*)&aux2[gidx];
#pragma unroll
          for (int t = 0; t < 4; t++){
            o[t]     = f2bf((v0[t] + bf2f(ry8[t]))     * (1.0f / 3.0f));
            o[t + 4] = f2bf((v1[t] + bf2f(ry8[t + 4])) * (1.0f / 3.0f));
          }
        } else {
#pragma unroll
          for (int t = 0; t < 4; t++){
            o[t] = f2bf(v0[t]); o[t + 4] = f2bf(v1[t]);
          }
        }
        *(u16x8*)&((unsigned short*)outp)[gidx] = o;
      }
    } else {
#pragma unroll
      for (int s = 0; s < 8; s++){
        const int lrow = 2 * s + (lane >> 5);
        const int grow = m0 + wm * 64 + i * 16 + lrow;
        const int lcol = (lane & 31) * 4;
        f32x4 v = *(const f32x4*)(ew + lrow * 132 + lcol);
        *(f32x4*)&((float*)outp)[(size_t)grow * N + n0 + wn * 128 + lcol] = v;
      }
    }
  }
}

extern "C" void kernel_launch(void* const* d_in, const int* in_sizes, int n_in,
                              void* d_out, int out_size, void* d_ws, size_t ws_size,
                              hipStream_t stream)
{
  const float* x    = (const float*)d_in[0];
  const float* aW1  = (const float*)d_in[1];
  const float* ab1  = (const float*)d_in[2];
  const float* ag1  = (const float*)d_in[3];
  const float* abe1 = (const float*)d_in[4];
  const float* aW2  = (const float*)d_in[5];
  const float* ab2  = (const float*)d_in[6];
  const float* ag2  = (const float*)d_in[7];
  const float* abe2 = (const float*)d_in[8];
  const float* aW3  = (const float*)d_in[9];
  const float* ab3  = (const float*)d_in[10];
  const float* pW1  = (const float*)d_in[11];
  const float* pb1  = (const float*)d_in[12];
  const float* pg1  = (const float*)d_in[13];
  const float* pbe1 = (const float*)d_in[14];
  const float* pW2  = (const float*)d_in[15];
  const float* pb2  = (const float*)d_in[16];
  const float* rfreq  = (const float*)d_in[17];
  const float* rphase = (const float*)d_in[18];
  const float* aiw  = (const float*)d_in[19];
  const float* aib  = (const float*)d_in[20];
  const float* aow  = (const float*)d_in[21];
  const float* aob  = (const float*)d_in[22];

  const int B = 16384, Q = 1024;

  // ---- workspace layout (~188 MB; c2 lives in d_out) ----
  char* ws = (char*)d_ws;
  size_t off = 0;
  auto alloc = [&](size_t bytes) -> char* {
    char* ptr = ws + off; off += (bytes + 255) & ~(size_t)255; return ptr;
  };
  unsigned short* Wb2  = (unsigned short*)alloc((size_t)2 * Q * 4 * Q * 2); // 16 MB
  unsigned short* Wb3  = (unsigned short*)alloc((size_t)Q * 2 * Q * 2);     //  4 MB
  unsigned short* PWb2 = (unsigned short*)alloc((size_t)Q * 2 * Q * 2);     //  4 MB
  unsigned short* WVb  = (unsigned short*)alloc((size_t)Q * Q * 2);         //  2 MB
  unsigned short* WOb  = (unsigned short*)alloc((size_t)Q * Q * 2);         //  2 MB
  unsigned short* R1   = (unsigned short*)alloc((size_t)B * 4 * Q * 2);     // 128 MB shared region
  unsigned short* ry   = (unsigned short*)alloc((size_t)B * Q * 2);         //  32 MB

  // R1 overlays (time-disjoint):
  unsigned short* p  = R1;                      // phase act (dead after gemm_ph)
  unsigned short* h  = R1;                      // amp act   (dead after gemm1)
  unsigned short* qs = R1;                      // combine out (after h dead)
  unsigned short* v  = R1 + (size_t)B * Q;      // v (after h dead)
  unsigned short* c2 = (unsigned short*)d_out;  // borrow output buffer (64 MB), dead before final GEMM

  // weight converts (bf16)
  cvt_bf16<<<(2*Q*4*Q + 255) / 256, 256, 0, stream>>>(aW2, Wb2, 2*Q*4*Q);
  cvt_bf16<<<(Q*2*Q + 255) / 256, 256, 0, stream>>>(aW3, Wb3, Q*2*Q);
  cvt_bf16<<<(Q*2*Q + 255) / 256, 256, 0, stream>>>(pW2, PWb2, Q*2*Q);
  cvt_bf16<<<(Q*Q + 255) / 256, 256, 0, stream>>>(aiw + (size_t)2*Q*Q, WVb, Q*Q);
  cvt_bf16<<<(Q*Q + 255) / 256, 256, 0, stream>>>(aow, WOb, Q*Q);

  const float* rf4 = rfreq  + (size_t)4 * Q * 3;   // rot_freq[-1]
  const float* rp4 = rphase + (size_t)4 * Q * 3;   // rot_phase[-1]

  const int mT = B / 256;          // 64
  const int nT1 = 2 * Q / 256;     // 8
  const int nTq = Q / 256;         // 4

  // ---- phase path first (so p's region can be reused by h) ----
  front_ph_kernel<<<B, 256, 0, stream>>>(x, pW1, pb1, pg1, pbe1, p);
  // ry = cos(tanh(p@pW2.T + pb2)*rf1 + rp1)   (N=1024, K=2048)
  gemm_bt<2><<<nTq * mT, 512, 0, stream>>>(p, PWb2, ry, B, Q, 2*Q, nTq,
                                           pb2, rf4, rp4, nullptr);

  // ---- amp path ----
  front_amp_kernel<<<B, 256, 0, stream>>>(x, aW1, ab1, ag1, abe1, h);
  // GEMM1: c2 = h @ aW2.T + b2   (M=16384, N=2048, K=4096), bf16 out (in d_out)
  gemm_bt<0><<<nT1 * mT, 512, 0, stream>>>(h, Wb2, c2, B, 2*Q, 4*Q, nT1,
                                           ab2, nullptr, nullptr, nullptr);
  // h2 = tanh(LN(c2)) in place
  ln_tanh_kernel<<<B, 256, 0, stream>>>(c2, ag2, abe2);

  // GEMM2 (fused combine): qs = (sin((c2h@aW3.T+b3)*rf0+rp0) + ry + tanh(rp2))/3
  gemm_bt<1><<<nTq * mT, 512, 0, stream>>>(c2, Wb3, qs, B, Q, 2*Q, nTq,
                                           ab3, rf4, rp4, ry);
  // GEMM4: v = qs @ aiw[2Q:].T + aib[2Q:]   (N=1024, K=1024)
  gemm_bt<0><<<nTq * mT, 512, 0, stream>>>(qs, WVb, v, B, Q, Q, nTq,
                                           aib + 2*Q, nullptr, nullptr, nullptr);
  // GEMM5: out = v @ aow.T + aob   (N=1024, K=1024), fp32 out (overwrites dead c2)
  gemm_bt<3><<<nTq * mT, 512, 0, stream>>>(v, WOb, d_out, B, Q, Q, nTq,
                                           aob, nullptr, nullptr, nullptr);
}

// Round 8
// 904.448 us; speedup vs baseline: 1.0219x; 1.0032x over previous
//
#include <hip/hip_runtime.h>

using bf16x8 = __attribute__((ext_vector_type(8))) __bf16;
using u16x8  = __attribute__((ext_vector_type(8))) unsigned short;
using f32x4  = __attribute__((ext_vector_type(4))) float;

__device__ __forceinline__ unsigned short f2bf(float f){
  unsigned int u = __float_as_uint(f);
  u += 0x7fffu + ((u >> 16) & 1u);     // round-to-nearest-even
  return (unsigned short)(u >> 16);
}
__device__ __forceinline__ float bf2f(unsigned short h){
  return __uint_as_float(((unsigned int)h) << 16);
}

// ---------------- weight fp32 -> bf16 convert ----------------
__global__ __launch_bounds__(256) void cvt_bf16(const float* __restrict__ s,
                                                unsigned short* __restrict__ d, int n){
  int i = blockIdx.x * 256 + threadIdx.x;
  if (i < n) d[i] = f2bf(s[i]);
}

// ---------------- front (amp): h = gelu(LN(x@aW1.T + b1)) ----------------
__global__ __launch_bounds__(256) void front_amp_kernel(
    const float* __restrict__ x,
    const float* __restrict__ W1, const float* __restrict__ b1,
    const float* __restrict__ g1, const float* __restrict__ be1,
    unsigned short* __restrict__ h)
{
  __shared__ float red[256];
  __shared__ float red2[256];
  __shared__ float s_mean, s_inv;
  const int row = blockIdx.x;
  const int tid = threadIdx.x;
  const float x0 = x[row * 2 + 0];
  const float x1 = x[row * 2 + 1];

  const f32x4* W4 = (const f32x4*)(W1 + (size_t)tid * 32);   // 8 x f32x4
  float va[16];
  float sum = 0.f, sq = 0.f;
#pragma unroll
  for (int i4 = 0; i4 < 4; i4++){
    f32x4 b4 = *(const f32x4*)(b1 + tid * 16 + i4 * 4);
    f32x4 wa = W4[i4 * 2], wb = W4[i4 * 2 + 1];
    float v0 = x0 * wa[0] + x1 * wa[1] + b4[0];
    float v1 = x0 * wa[2] + x1 * wa[3] + b4[1];
    float v2 = x0 * wb[0] + x1 * wb[1] + b4[2];
    float v3 = x0 * wb[2] + x1 * wb[3] + b4[3];
    va[i4*4+0] = v0; va[i4*4+1] = v1; va[i4*4+2] = v2; va[i4*4+3] = v3;
    sum += v0 + v1 + v2 + v3;
    sq  += v0*v0 + v1*v1 + v2*v2 + v3*v3;
  }
  red[tid] = sum; red2[tid] = sq; __syncthreads();
  for (int s = 128; s > 0; s >>= 1){
    if (tid < s){ red[tid] += red[tid + s]; red2[tid] += red2[tid + s]; }
    __syncthreads();
  }
  if (tid == 0){
    float m = red[0] * (1.0f / 4096.0f);
    float v = red2[0] * (1.0f / 4096.0f) - m * m;
    s_mean = m; s_inv = rsqrtf(v + 1e-5f);
  }
  __syncthreads();
  float mean = s_mean, inv = s_inv;
#pragma unroll
  for (int i8 = 0; i8 < 2; i8++){
    f32x4 ga = *(const f32x4*)(g1  + tid * 16 + i8 * 8);
    f32x4 gb = *(const f32x4*)(g1  + tid * 16 + i8 * 8 + 4);
    f32x4 ba = *(const f32x4*)(be1 + tid * 16 + i8 * 8);
    f32x4 bb = *(const f32x4*)(be1 + tid * 16 + i8 * 8 + 4);
    u16x8 o;
#pragma unroll
    for (int k = 0; k < 8; k++){
      float gk = (k < 4) ? ga[k] : gb[k - 4];
      float bk = (k < 4) ? ba[k] : bb[k - 4];
      float y = (va[i8 * 8 + k] - mean) * inv * gk + bk;
      float ge = 0.5f * y * (1.0f + erff(y * 0.70710678118654752f));
      o[k] = f2bf(ge);
    }
    *(u16x8*)&h[(size_t)row * 4096 + tid * 16 + i8 * 8] = o;
  }
}

// ---------------- front (phase): p = silu(LN(x@pW1.T + b1)) ----------------
__global__ __launch_bounds__(256) void front_ph_kernel(
    const float* __restrict__ x,
    const float* __restrict__ W1, const float* __restrict__ b1,
    const float* __restrict__ g1, const float* __restrict__ be1,
    unsigned short* __restrict__ p)
{
  __shared__ float red[256];
  __shared__ float red2[256];
  __shared__ float s_mean, s_inv;
  const int row = blockIdx.x;
  const int tid = threadIdx.x;
  const float x0 = x[row * 2 + 0];
  const float x1 = x[row * 2 + 1];

  const f32x4* W4 = (const f32x4*)(W1 + (size_t)tid * 16);   // 4 x f32x4
  float vp[8];
  float sum = 0.f, sq = 0.f;
#pragma unroll
  for (int i4 = 0; i4 < 2; i4++){
    f32x4 b4 = *(const f32x4*)(b1 + tid * 8 + i4 * 4);
    f32x4 wa = W4[i4 * 2], wb = W4[i4 * 2 + 1];
    float v0 = x0 * wa[0] + x1 * wa[1] + b4[0];
    float v1 = x0 * wa[2] + x1 * wa[3] + b4[1];
    float v2 = x0 * wb[0] + x1 * wb[1] + b4[2];
    float v3 = x0 * wb[2] + x1 * wb[3] + b4[3];
    vp[i4*4+0] = v0; vp[i4*4+1] = v1; vp[i4*4+2] = v2; vp[i4*4+3] = v3;
    sum += v0 + v1 + v2 + v3;
    sq  += v0*v0 + v1*v1 + v2*v2 + v3*v3;
  }
  red[tid] = sum; red2[tid] = sq; __syncthreads();
  for (int s = 128; s > 0; s >>= 1){
    if (tid < s){ red[tid] += red[tid + s]; red2[tid] += red2[tid + s]; }
    __syncthreads();
  }
  if (tid == 0){
    float m = red[0] * (1.0f / 2048.0f);
    float v = red2[0] * (1.0f / 2048.0f) - m * m;
    s_mean = m; s_inv = rsqrtf(v + 1e-5f);
  }
  __syncthreads();
  float mean = s_mean, inv = s_inv;
  {
    f32x4 ga = *(const f32x4*)(g1  + tid * 8);
    f32x4 gb = *(const f32x4*)(g1  + tid * 8 + 4);
    f32x4 ba = *(const f32x4*)(be1 + tid * 8);
    f32x4 bb = *(const f32x4*)(be1 + tid * 8 + 4);
    u16x8 o;
#pragma unroll
    for (int k = 0; k < 8; k++){
      float gk = (k < 4) ? ga[k] : gb[k - 4];
      float bk = (k < 4) ? ba[k] : bb[k - 4];
      float y = (vp[k] - mean) * inv * gk + bk;
      float si = y / (1.0f + expf(-y));
      o[k] = f2bf(si);
    }
    *(u16x8*)&p[(size_t)row * 2048 + tid * 8] = o;
  }
}

// ---------------- row-wise LN + tanh, in place on bf16 (N=2048) ----------------
__global__ __launch_bounds__(256) void ln_tanh_kernel(
    unsigned short* __restrict__ c, const float* __restrict__ g,
    const float* __restrict__ be)
{
  __shared__ float red[256];
  __shared__ float red2[256];
  __shared__ float s_mean, s_inv;
  const size_t base = (size_t)blockIdx.x * 2048;
  const int tid = threadIdx.x;
  u16x8 cv = *(const u16x8*)&c[base + tid * 8];
  float v[8];
  float sum = 0.f, sq = 0.f;
#pragma unroll
  for (int k = 0; k < 8; k++){
    float t = bf2f(cv[k]);
    v[k] = t; sum += t; sq += t * t;
  }
  red[tid] = sum; red2[tid] = sq; __syncthreads();
  for (int s = 128; s > 0; s >>= 1){
    if (tid < s){ red[tid] += red[tid + s]; red2[tid] += red2[tid + s]; }
    __syncthreads();
  }
  if (tid == 0){
    float m = red[0] * (1.0f / 2048.0f);
    float vv = red2[0] * (1.0f / 2048.0f) - m * m;
    s_mean = m; s_inv = rsqrtf(vv + 1e-5f);
  }
  __syncthreads();
  float mean = s_mean, inv = s_inv;
  {
    f32x4 ga = *(const f32x4*)(g  + tid * 8);
    f32x4 gb = *(const f32x4*)(g  + tid * 8 + 4);
    f32x4 ba = *(const f32x4*)(be + tid * 8);
    f32x4 bb = *(const f32x4*)(be + tid * 8 + 4);
    u16x8 o;
#pragma unroll
    for (int k = 0; k < 8; k++){
      float gk = (k < 4) ? ga[k] : gb[k - 4];
      float bk = (k < 4) ? ba[k] : bb[k - 4];
      float y = (v[k] - mean) * inv * gk + bk;
      o[k] = f2bf(tanhf(y));
    }
    *(u16x8*)&c[base + tid * 8] = o;
  }
}

// ---------------- bf16 MFMA GEMM: C = A @ B^T (+epilogue) ----------------
// 256x256 block tile, 512 thr = 8 waves (4m x 2n), wave = 64x128 out.
//
// R13: 8-PHASE SCHEDULE (m201 template port). R1/R2/R7 all plateaued at
// MfmaUtil 48% — barrier-locked waves put every wave in its read cluster
// simultaneously, so LDS time and MFMA time ADD. The m201 structure
// (verified 1563 TF @4k) interleaves at 16-MFMA granularity with barrier
// pairs + counted vmcnt so the stage stall amortizes and LDS-read leaves
// the critical path. Geometry here: BK=64 K-tiles, 2 LDS buffers (64KB),
// each K-tile = two BK=32 sub-tiles [256][32] using the PROVEN
// conflict-free layout/swizzle (bank-conflict = 0 measured). Per K-tile:
// 4 phases {4-8 ds_read + 1 stage-unit(2 glds) -> barrier -> lgkmcnt(0)
// +sched_barrier(0) -> setprio+16 MFMA -> barrier}. Stage-units lead
// consumption by 6 units; ONE counted WAITV4 per iter (ph3 trailing)
// certifies the next tile — never drains. Ledger: every overwritten LDS
// region's last reader is >=2 phase-barriers before the glds issue
// (A-kk0 read@ph0/overwritten@ph2+iter; B-kk0 read@ph0,1/ow@ph3+iter;
// A-kk1 read@ph2/ow@ph0+2iter; B-kk1 read@ph2,3/ow@ph1+2iter);
// wait-THEN-barrier preserved; guards wave-uniform; K-order per acc
// element unchanged -> bit-identical output.
// EPI: 0 = bf16(val + bias[col])
//      1 = bf16((sin((val+bias)*rf0+rp0) + ry + tanh(rp2))/3)  [aux2=ry]
//      2 = bf16(cos(tanh(val+bias)*rf1 + rp1))                 [phase ry]
//      3 = f32(val + bias[col])                                [final]

#define WAITV4() asm volatile("s_waitcnt vmcnt(4)" ::: "memory")
#define WAITV0() asm volatile("s_waitcnt vmcnt(0)" ::: "memory")
#define LGKM0()  do { asm volatile("s_waitcnt lgkmcnt(0)" ::: "memory"); \
                      __builtin_amdgcn_sched_barrier(0); } while(0)

template<int EPI>
__global__ __launch_bounds__(512, 2) void gemm_bt(
    const unsigned short* __restrict__ A, const unsigned short* __restrict__ B,
    void* __restrict__ outp, int M, int N, int K, int nT,
    const float* __restrict__ bias,
    const float* __restrict__ aux0, const float* __restrict__ aux1,
    const unsigned short* __restrict__ aux2)
{
  __shared__ __align__(16) char smem_raw[131072];  // 2 bufs x 64KB (A 2x16K + B 2x16K)
  unsigned short* S = (unsigned short*)smem_raw;

  const int tid  = threadIdx.x;
  const int wave = tid >> 6, lane = tid & 63;
  const int wm = wave >> 1, wn = wave & 1;     // wm 0..3 (64-row band), wn 0..1 (128-col band)
  const int lm = lane & 15, lq = lane >> 4;

  int lid = blockIdx.x;
  {
    const int nwg = gridDim.x;                 // 512 or 256 here: always %8==0
    if ((nwg & 7) == 0) lid = (lid & 7) * (nwg >> 3) + (lid >> 3);
  }
  const int m0 = (lid / nT) * 256, n0 = (lid % nT) * 256;

  f32x4 acc[4][8];
#pragma unroll
  for (int i = 0; i < 4; i++)
#pragma unroll
    for (int j = 0; j < 8; j++) acc[i][j] = (f32x4){0.f, 0.f, 0.f, 0.f};

  // staging: lane covers row (wave*32 + lr), 16B unit (lane&3) XOR-swizzled by
  // row within each 32-col sub-tile (proven conflict-free layout).
  const int lr = lane >> 2;
  const int lc = (((lane & 3) ^ ((lr >> 1) & 3)) << 3);
  const unsigned short* gA = A + (size_t)(m0 + wave * 32 + lr) * K + lc;
  const unsigned short* gB = B + (size_t)(n0 + wave * 32 + lr) * K + lc;
  const size_t rowK16 = (size_t)16 * K;

  // sub-tile layout: [buf:32768][A kk:8192 | B base 16384 + kk:8192] units
  auto stageA = [&](int buf, int kk, int tile){
    unsigned short* d = S + buf * 32768 + kk * 8192 + wave * 1024;
    const unsigned short* s = gA + (size_t)tile * 64 + kk * 32;
    __builtin_amdgcn_global_load_lds(
        (const __attribute__((address_space(1))) void*)s,
        (__attribute__((address_space(3))) void*)d, 16, 0, 0);
    __builtin_amdgcn_global_load_lds(
        (const __attribute__((address_space(1))) void*)(s + rowK16),
        (__attribute__((address_space(3))) void*)(d + 512), 16, 0, 0);
  };
  auto stageB = [&](int buf, int kk, int tile){
    unsigned short* d = S + buf * 32768 + 16384 + kk * 8192 + wave * 1024;
    const unsigned short* s = gB + (size_t)tile * 64 + kk * 32;
    __builtin_amdgcn_global_load_lds(
        (const __attribute__((address_space(1))) void*)s,
        (__attribute__((address_space(3))) void*)d, 16, 0, 0);
    __builtin_amdgcn_global_load_lds(
        (const __attribute__((address_space(1))) void*)(s + rowK16),
        (__attribute__((address_space(3))) void*)(d + 512), 16, 0, 0);
  };

  auto readA4 = [&](int buf, int kk, bf16x8* af){
    const unsigned short* sA = S + buf * 32768 + kk * 8192;
#pragma unroll
    for (int q = 0; q < 4; q++){
      const int r = wm * 64 + q * 16 + lm;
      af[q] = *(const bf16x8*)&sA[r * 32 + ((lq ^ ((r >> 1) & 3)) << 3)];
    }
  };
  auto readB4 = [&](int buf, int kk, int jh, bf16x8* bf){
    const unsigned short* sB = S + buf * 32768 + 16384 + kk * 8192;
#pragma unroll
    for (int q = 0; q < 4; q++){
      const int r = wn * 128 + jh * 64 + q * 16 + lm;
      bf[q] = *(const bf16x8*)&sB[r * 32 + ((lq ^ ((r >> 1) & 3)) << 3)];
    }
  };

  auto mfma16 = [&](int jh, const bf16x8* af, const bf16x8* bf){
    __builtin_amdgcn_s_setprio(1);
#pragma unroll
    for (int i = 0; i < 4; i++)
#pragma unroll
      for (int q = 0; q < 4; q++)
        acc[i][jh * 4 + q] =
            __builtin_amdgcn_mfma_f32_16x16x32_bf16(af[i], bf[q], acc[i][jh * 4 + q], 0, 0, 0);
    __builtin_amdgcn_s_setprio(0);
  };

  const int nT64 = K >> 6;         // 64 / 32 / 16 here (always >= 2)
  bf16x8 af[4], bf[4];

  // prologue: tile0 fully + tile1's A0,B0 (newest 4 loads stay in flight)
  stageA(0, 0, 0); stageB(0, 0, 0); stageA(0, 1, 0); stageB(0, 1, 0);
  stageA(1, 0, 1); stageB(1, 0, 1);
  WAITV4();                        // certify tile 0 (own wave)
  __builtin_amdgcn_s_barrier();    // cross-wave

  for (int t = 0; t < nT64; ++t){
    const int c = t & 1;
    // ---- ph0: A-kk0 + B-kk0-jh0 reads; stage A1(t+1) ----
    readA4(c, 0, af); readB4(c, 0, 0, bf);
    if (t + 1 < nT64) stageA(c ^ 1, 1, t + 1);
    __builtin_amdgcn_s_barrier();
    LGKM0();
    mfma16(0, af, bf);
    __builtin_amdgcn_s_barrier();
    // ---- ph1: B-kk0-jh1 reads; stage B1(t+1) ----
    readB4(c, 0, 1, bf);
    if (t + 1 < nT64) stageB(c ^ 1, 1, t + 1);
    __builtin_amdgcn_s_barrier();
    LGKM0();
    mfma16(1, af, bf);
    __builtin_amdgcn_s_barrier();
    // ---- ph2: A-kk1 + B-kk1-jh0 reads; stage A0(t+2) ----
    readA4(c, 1, af); readB4(c, 1, 0, bf);
    if (t + 2 < nT64) stageA(c, 0, t + 2);
    __builtin_amdgcn_s_barrier();
    LGKM0();
    mfma16(0, af, bf);
    __builtin_amdgcn_s_barrier();
    // ---- ph3: B-kk1-jh1 reads; stage B0(t+2); counted cert for tile t+1 ----
    readB4(c, 1, 1, bf);
    if (t + 2 < nT64) stageB(c, 0, t + 2);
    __builtin_amdgcn_s_barrier();
    LGKM0();
    mfma16(1, af, bf);
    if (t + 2 < nT64) WAITV4(); else WAITV0();   // certify tile t+1 (own wave)
    __builtin_amdgcn_s_barrier();                // cross-wave cert + phase seal
  }

  // ---- epilogue: per-wave LDS transpose -> coalesced stores ----
  __syncthreads();                 // all waves done reading staging LDS
  float* ew = (float*)smem_raw + wave * 2112;   // 16 rows x stride 132

#pragma unroll
  for (int i = 0; i < 4; i++){
    // phase 1: epilogue math (col params known), write fp32 to private LDS chunk
#pragma unroll
    for (int j = 0; j < 8; j++){
      const int col = n0 + wn * 128 + j * 16 + lm;
      float bcol = bias[col];
      float f0 = 0.f, p0 = 0.f, rzv = 0.f;
      if constexpr (EPI == 1){
        f0 = aux0[3 * col]; p0 = aux1[3 * col]; rzv = tanhf(aux1[3 * col + 2]);
      }
      if constexpr (EPI == 2){
        f0 = aux0[3 * col + 1]; p0 = aux1[3 * col + 1];
      }
#pragma unroll
      for (int r = 0; r < 4; r++){
        const float val = acc[i][j][r];
        float pre;
        if constexpr (EPI == 0 || EPI == 3)      pre = val + bcol;
        else if constexpr (EPI == 1)             pre = sinf((val + bcol) * f0 + p0) + rzv;
        else                                     pre = cosf(tanhf(val + bcol) * f0 + p0);
        ew[(lq * 4 + r) * 132 + j * 16 + lm] = pre;
      }
    }
    // phase 2: read back rows, store coalesced (same wave wrote -> no barrier)
    if constexpr (EPI != 3){
#pragma unroll
      for (int s = 0; s < 4; s++){
        const int lrow = 4 * s + lq;
        const int grow = m0 + wm * 64 + i * 16 + lrow;
        const float* src = ew + lrow * 132 + lm * 8;
        f32x4 v0 = *(const f32x4*)(src);
        f32x4 v1 = *(const f32x4*)(src + 4);
        const size_t gidx = (size_t)grow * N + n0 + wn * 128 + lm * 8;
        u16x8 o;
        if constexpr (EPI == 1){
          u16x8 ry8 = *(const u16x8*)&aux2[gidx];
#pragma unroll
          for (int t = 0; t < 4; t++){
            o[t]     = f2bf((v0[t] + bf2f(ry8[t]))     * (1.0f / 3.0f));
            o[t + 4] = f2bf((v1[t] + bf2f(ry8[t + 4])) * (1.0f / 3.0f));
          }
        } else {
#pragma unroll
          for (int t = 0; t < 4; t++){
            o[t] = f2bf(v0[t]); o[t + 4] = f2bf(v1[t]);
          }
        }
        *(u16x8*)&((unsigned short*)outp)[gidx] = o;
      }
    } else {
#pragma unroll
      for (int s = 0; s < 8; s++){
        const int lrow = 2 * s + (lane >> 5);
        const int grow = m0 + wm * 64 + i * 16 + lrow;
        const int lcol = (lane & 31) * 4;
        f32x4 v = *(const f32x4*)(ew + lrow * 132 + lcol);
        *(f32x4*)&((float*)outp)[(size_t)grow * N + n0 + wn * 128 + lcol] = v;
      }
    }
  }
}

extern "C" void kernel_launch(void* const* d_in, const int* in_sizes, int n_in,
                              void* d_out, int out_size, void* d_ws, size_t ws_size,
                              hipStream_t stream)
{
  const float* x    = (const float*)d_in[0];
  const float* aW1  = (const float*)d_in[1];
  const float* ab1  = (const float*)d_in[2];
  const float* ag1  = (const float*)d_in[3];
  const float* abe1 = (const float*)d_in[4];
  const float* aW2  = (const float*)d_in[5];
  const float* ab2  = (const float*)d_in[6];
  const float* ag2  = (const float*)d_in[7];
  const float* abe2 = (const float*)d_in[8];
  const float* aW3  = (const float*)d_in[9];
  const float* ab3  = (const float*)d_in[10];
  const float* pW1  = (const float*)d_in[11];
  const float* pb1  = (const float*)d_in[12];
  const float* pg1  = (const float*)d_in[13];
  const float* pbe1 = (const float*)d_in[14];
  const float* pW2  = (const float*)d_in[15];
  const float* pb2  = (const float*)d_in[16];
  const float* rfreq  = (const float*)d_in[17];
  const float* rphase = (const float*)d_in[18];
  const float* aiw  = (const float*)d_in[19];
  const float* aib  = (const float*)d_in[20];
  const float* aow  = (const float*)d_in[21];
  const float* aob  = (const float*)d_in[22];

  const int B = 16384, Q = 1024;

  // ---- workspace layout (~188 MB; c2 lives in d_out) ----
  char* ws = (char*)d_ws;
  size_t off = 0;
  auto alloc = [&](size_t bytes) -> char* {
    char* ptr = ws + off; off += (bytes + 255) & ~(size_t)255; return ptr;
  };
  unsigned short* Wb2  = (unsigned short*)alloc((size_t)2 * Q * 4 * Q * 2); // 16 MB
  unsigned short* Wb3  = (unsigned short*)alloc((size_t)Q * 2 * Q * 2);     //  4 MB
  unsigned short* PWb2 = (unsigned short*)alloc((size_t)Q * 2 * Q * 2);     //  4 MB
  unsigned short* WVb  = (unsigned short*)alloc((size_t)Q * Q * 2);         //  2 MB
  unsigned short* WOb  = (unsigned short*)alloc((size_t)Q * Q * 2);         //  2 MB
  unsigned short* R1   = (unsigned short*)alloc((size_t)B * 4 * Q * 2);     // 128 MB shared region
  unsigned short* ry   = (unsigned short*)alloc((size_t)B * Q * 2);         //  32 MB

  // R1 overlays (time-disjoint):
  unsigned short* p  = R1;                      // phase act (dead after gemm_ph)
  unsigned short* h  = R1;                      // amp act   (dead after gemm1)
  unsigned short* qs = R1;                      // combine out (after h dead)
  unsigned short* v  = R1 + (size_t)B * Q;      // v (after h dead)
  unsigned short* c2 = (unsigned short*)d_out;  // borrow output buffer (64 MB), dead before final GEMM

  // weight converts (bf16)
  cvt_bf16<<<(2*Q*4*Q + 255) / 256, 256, 0, stream>>>(aW2, Wb2, 2*Q*4*Q);
  cvt_bf16<<<(Q*2*Q + 255) / 256, 256, 0, stream>>>(aW3, Wb3, Q*2*Q);
  cvt_bf16<<<(Q*2*Q + 255) / 256, 256, 0, stream>>>(pW2, PWb2, Q*2*Q);
  cvt_bf16<<<(Q*Q + 255) / 256, 256, 0, stream>>>(aiw + (size_t)2*Q*Q, WVb, Q*Q);
  cvt_bf16<<<(Q*Q + 255) / 256, 256, 0, stream>>>(aow, WOb, Q*Q);

  const float* rf4 = rfreq  + (size_t)4 * Q * 3;   // rot_freq[-1]
  const float* rp4 = rphase + (size_t)4 * Q * 3;   // rot_phase[-1]

  const int mT = B / 256;          // 64
  const int nT1 = 2 * Q / 256;     // 8
  const int nTq = Q / 256;         // 4

  // ---- phase path first (so p's region can be reused by h) ----
  front_ph_kernel<<<B, 256, 0, stream>>>(x, pW1, pb1, pg1, pbe1, p);
  // ry = cos(tanh(p@pW2.T + pb2)*rf1 + rp1)   (N=1024, K=2048)
  gemm_bt<2><<<nTq * mT, 512, 0, stream>>>(p, PWb2, ry, B, Q, 2*Q, nTq,
                                           pb2, rf4, rp4, nullptr);

  // ---- amp path ----
  front_amp_kernel<<<B, 256, 0, stream>>>(x, aW1, ab1, ag1, abe1, h);
  // GEMM1: c2 = h @ aW2.T + b2   (M=16384, N=2048, K=4096), bf16 out (in d_out)
  gemm_bt<0><<<nT1 * mT, 512, 0, stream>>>(h, Wb2, c2, B, 2*Q, 4*Q, nT1,
                                           ab2, nullptr, nullptr, nullptr);
  // h2 = tanh(LN(c2)) in place
  ln_tanh_kernel<<<B, 256, 0, stream>>>(c2, ag2, abe2);

  // GEMM2 (fused combine): qs = (sin((c2h@aW3.T+b3)*rf0+rp0) + ry + tanh(rp2))/3
  gemm_bt<1><<<nTq * mT, 512, 0, stream>>>(c2, Wb3, qs, B, Q, 2*Q, nTq,
                                           ab3, rf4, rp4, ry);
  // GEMM4: v = qs @ aiw[2Q:].T + aib[2Q:]   (N=1024, K=1024)
  gemm_bt<0><<<nTq * mT, 512, 0, stream>>>(qs, WVb, v, B, Q, Q, nTq,
                                           aib + 2*Q, nullptr, nullptr, nullptr);
  // GEMM5: out = v @ aow.T + aob   (N=1024, K=1024), fp32 out (overwrites dead c2)
  gemm_bt<3><<<nTq * mT, 512, 0, stream>>>(v, WOb, d_out, B, Q, Q, nTq,
                                           aob, nullptr, nullptr, nullptr);
}